// Round 5
// baseline (463.590 us; speedup 1.0000x reference)
//
#include <hip/hip_runtime.h>

// Sinkhorn-Knopp on B independent 8x8 fp32 matrices.
//
// R5 = R3/R4 with the nontemporal-store compile error fixed: clang's
// __builtin_nontemporal_store requires a native vector type, not HIP's
// HIP_vector_type<float,4> struct -> use ext_vector_type(4) float.
//
// Layout: one full ROW per lane, TWO matrices per thread, zero DS ops.
//
// Within a 16-lane group (t = lane & 15):
//   row bits  = lane bits {0,1,3}:  row = (t&3) | ((t>>1)&4)
//   matrix-of-pair = lane bit 2:    b = (t>>2)&1
// A wave (64 lanes = 4 groups) holds 8 matrices per chain; each thread runs
// two independent chains (A at wave base, B at +8 matrices) -> 16 matrices
// per wave.
//
// Row normalize: fully lane-local (7 add + 1 rcp + 8 mul), no cross-lane op.
// Col normalize: butterfly all-reduce across the 8 rows = lane xor {1,2,8}:
//   xor1 -> DPP quad_perm [1,0,3,2] (0xB1)
//   xor2 -> DPP quad_perm [2,3,0,1] (0x4E)
//   xor8 -> DPP row_ror:8 (0x128)
// All cross-lane traffic is DPP on the VALU; the DS pipe is never touched.
//
// ~250 VALU + ~53 trans instr/thread for 16 matrices/wave ≈ 15 cyc/matrix/CU
// of issue pressure vs the ~50 cyc/matrix/CU HBM floor -> memory-bound.
// Target: 512 MiB / ~6.3 TB/s ≈ 85 us.

#define N 8

typedef float f32x4 __attribute__((ext_vector_type(4)));

template <int CTRL>
__device__ __forceinline__ float dpp_xor(float x) {
    int r = __builtin_amdgcn_update_dpp(0, __float_as_int(x), CTRL, 0xF, 0xF, true);
    return __int_as_float(r);
}

__device__ __forceinline__ void load_exp(const f32x4* __restrict__ x4,
                                         size_t idx, float* r) {
    f32x4 v0 = x4[idx];
    f32x4 v1 = x4[idx + 1];
    r[0] = __expf(v0.x); r[1] = __expf(v0.y);
    r[2] = __expf(v0.z); r[3] = __expf(v0.w);
    r[4] = __expf(v1.x); r[5] = __expf(v1.y);
    r[6] = __expf(v1.z); r[7] = __expf(v1.w);
}

__device__ __forceinline__ void row_norm(float* r) {
    float s = ((r[0] + r[1]) + (r[2] + r[3])) + ((r[4] + r[5]) + (r[6] + r[7]));
    float inv = __builtin_amdgcn_rcpf(s);
#pragma unroll
    for (int i = 0; i < 8; ++i) r[i] *= inv;
}

__device__ __forceinline__ void col_norm(float* r) {
    float c[8];
#pragma unroll
    for (int i = 0; i < 8; ++i) c[i] = r[i];
#pragma unroll
    for (int i = 0; i < 8; ++i) c[i] += dpp_xor<0xB1>(c[i]);
#pragma unroll
    for (int i = 0; i < 8; ++i) c[i] += dpp_xor<0x4E>(c[i]);
#pragma unroll
    for (int i = 0; i < 8; ++i) c[i] += dpp_xor<0x128>(c[i]);
#pragma unroll
    for (int i = 0; i < 8; ++i) r[i] *= __builtin_amdgcn_rcpf(c[i]);
}

__device__ __forceinline__ void store_row(f32x4* __restrict__ o4,
                                          size_t idx, const float* r) {
    f32x4 v0 = {r[0], r[1], r[2], r[3]};
    f32x4 v1 = {r[4], r[5], r[6], r[7]};
    __builtin_nontemporal_store(v0, &o4[idx]);
    __builtin_nontemporal_store(v1, &o4[idx + 1]);
}

__global__ __launch_bounds__(256) void sinkhorn8_kernel(
    const float* __restrict__ x,
    float* __restrict__ out,
    const int* __restrict__ num_iters_p,
    int nwaves)  // number of 16-matrix waves
{
    int T = blockIdx.x * blockDim.x + threadIdx.x;
    int w = T >> 6;  // wave id: handles matrices [w*16, w*16+16)
    if (w >= nwaves) return;

    const int num_iters = *num_iters_p;

    int l = T & 63;
    int g = l >> 4;          // 16-lane group -> matrix pair within chain
    int t = l & 15;
    int b = (t >> 2) & 1;    // which matrix of the pair
    int row = (t & 3) | ((t >> 1) & 4);

    // float4 index: matrix m occupies 16 float4s; lane's row = 2 of them.
    size_t idxA = (size_t)w * 256 + (size_t)g * 32 + (size_t)b * 16 + (size_t)row * 2;
    size_t idxB = idxA + 128;  // +8 matrices

    const f32x4* x4 = (const f32x4*)x;
    f32x4* o4 = (f32x4*)out;

    float A[8], Bv[8];
    load_exp(x4, idxA, A);
    load_exp(x4, idxB, Bv);

    for (int it = 0; it < num_iters; ++it) {
        row_norm(A);
        row_norm(Bv);
        col_norm(A);
        col_norm(Bv);
    }

    store_row(o4, idxA, A);
    store_row(o4, idxB, Bv);
}

extern "C" void kernel_launch(void* const* d_in, const int* in_sizes, int n_in,
                              void* d_out, int out_size, void* d_ws, size_t ws_size,
                              hipStream_t stream) {
    const float* x = (const float*)d_in[0];
    const int* num_iters = (const int*)d_in[1];
    float* out = (float*)d_out;

    int B = in_sizes[0] / (N * N);  // number of 8x8 matrices (1048576)
    int nwaves = B / 16;            // B is a multiple of 16 for this problem

    long long threads = (long long)nwaves * 64;
    int block = 256;
    long long grid = (threads + block - 1) / block;
    sinkhorn8_kernel<<<(int)grid, block, 0, stream>>>(x, out, num_iters, nwaves);
}

// Round 6
// 435.167 us; speedup vs baseline: 1.0653x; 1.0653x over previous
//
#include <hip/hip_runtime.h>

// Sinkhorn-Knopp on B independent 8x8 fp32 matrices.
//
// R6: row-per-lane DPP layout (as R5) with two fixes driven by R5 counters:
//  1. Plain stores instead of nontemporal: NT stores of this kernel's
//     strided half-line pattern (16B written per 32B per instr) bypassed L2
//     merging -> WRITE_SIZE 309MB vs 262MB ideal (+18% HBM write traffic).
//     Plain stores let L2 combine the complementary halves (R1: exact 256MiB).
//  2. FOUR matrices per thread (32 per wave): R5 was latency-bound
//     (VALUBusy 45%, HBM 41%, trans 13% -- nothing saturated) with only 2
//     dependency chains per thread across the 5 serial normalize iterations.
//     4 independent chains + all loads issued up-front doubles ILP and
//     halves wave count.
//
// Lane mapping within a 16-lane group (t = lane & 15):
//   row bits  = lane bits {0,1,3}:  row = (t&3) | ((t>>1)&4)
//   matrix-of-pair = lane bit 2:    b = (t>>2)&1
// Wave holds 8 matrices per chain x 4 chains = 32 matrices.
//
// Row normalize: fully lane-local (7 add + 1 rcp + 8 mul), no cross-lane op.
// Col normalize: butterfly all-reduce across the 8 rows = lane xor {1,2,8}:
//   xor1 -> DPP quad_perm [1,0,3,2] (0xB1)
//   xor2 -> DPP quad_perm [2,3,0,1] (0x4E)
//   xor8 -> DPP row_ror:8 (0x128)
// All cross-lane traffic is DPP on the VALU; the DS pipe is never touched.
//
// Memory floor: 512 MiB / ~6.3 TB/s ≈ 85 us (~205K cyc/CU); compute issue
// ≈ 122K cyc/CU -> memory-bound if overlap is good.

#define N 8

typedef float f32x4 __attribute__((ext_vector_type(4)));

template <int CTRL>
__device__ __forceinline__ float dpp_xor(float x) {
    int r = __builtin_amdgcn_update_dpp(0, __float_as_int(x), CTRL, 0xF, 0xF, true);
    return __int_as_float(r);
}

__device__ __forceinline__ void exp8(f32x4 v0, f32x4 v1, float* r) {
    r[0] = __expf(v0.x); r[1] = __expf(v0.y);
    r[2] = __expf(v0.z); r[3] = __expf(v0.w);
    r[4] = __expf(v1.x); r[5] = __expf(v1.y);
    r[6] = __expf(v1.z); r[7] = __expf(v1.w);
}

__device__ __forceinline__ void row_norm(float* r) {
    float s = ((r[0] + r[1]) + (r[2] + r[3])) + ((r[4] + r[5]) + (r[6] + r[7]));
    float inv = __builtin_amdgcn_rcpf(s);
#pragma unroll
    for (int i = 0; i < 8; ++i) r[i] *= inv;
}

__device__ __forceinline__ void col_norm(float* r) {
    // Per-element butterfly; 8 independent 3-deep DPP chains per matrix
    // (x4 chains across the thread) give the scheduler plenty to interleave.
#pragma unroll
    for (int i = 0; i < 8; ++i) {
        float c = r[i];
        c += dpp_xor<0xB1>(c);
        c += dpp_xor<0x4E>(c);
        c += dpp_xor<0x128>(c);
        r[i] *= __builtin_amdgcn_rcpf(c);
    }
}

__device__ __forceinline__ void store8(f32x4* __restrict__ o4, size_t idx,
                                       const float* r) {
    f32x4 v0 = {r[0], r[1], r[2], r[3]};
    f32x4 v1 = {r[4], r[5], r[6], r[7]};
    o4[idx] = v0;        // plain stores: let L2 merge the half-line pattern
    o4[idx + 1] = v1;
}

__global__ __launch_bounds__(256) void sinkhorn8_kernel(
    const float* __restrict__ x,
    float* __restrict__ out,
    const int* __restrict__ num_iters_p,
    int nwaves)  // number of 32-matrix waves
{
    int T = blockIdx.x * blockDim.x + threadIdx.x;
    int w = T >> 6;  // wave id: matrices [w*32, w*32+32)
    if (w >= nwaves) return;

    const int num_iters = *num_iters_p;

    int l = T & 63;
    int g = l >> 4;          // 16-lane group
    int t = l & 15;
    int b = (t >> 2) & 1;    // which matrix of the pair
    int row = (t & 3) | ((t >> 1) & 4);

    // float4 index of this lane's row in chain-A's matrix.
    size_t base = (size_t)w * 512 + (size_t)g * 32 + (size_t)b * 16 + (size_t)row * 2;

    const f32x4* x4 = (const f32x4*)x;
    f32x4* o4 = (f32x4*)out;

    // Issue all 8 loads up-front (4 chains x 2 dwordx4).
    f32x4 a0 = x4[base + 0],   a1 = x4[base + 1];
    f32x4 b0 = x4[base + 128], b1 = x4[base + 129];
    f32x4 c0 = x4[base + 256], c1 = x4[base + 257];
    f32x4 d0 = x4[base + 384], d1 = x4[base + 385];

    float A[8], Bv[8], C[8], D[8];
    exp8(a0, a1, A);
    exp8(b0, b1, Bv);
    exp8(c0, c1, C);
    exp8(d0, d1, D);

    for (int it = 0; it < num_iters; ++it) {
        row_norm(A); row_norm(Bv); row_norm(C); row_norm(D);
        col_norm(A); col_norm(Bv); col_norm(C); col_norm(D);
    }

    store8(o4, base + 0, A);
    store8(o4, base + 128, Bv);
    store8(o4, base + 256, C);
    store8(o4, base + 384, D);
}

// Tail (B % 32 != 0): one thread per matrix. Not launched for B = 1048576.
__global__ __launch_bounds__(64) void sinkhorn8_tail(
    const float* __restrict__ x,
    float* __restrict__ out,
    const int* __restrict__ num_iters_p,
    int nfull, int B)
{
    int m = nfull + blockIdx.x * blockDim.x + threadIdx.x;
    if (m >= B) return;
    const int num_iters = *num_iters_p;

    float M[N * N];
    const f32x4* xv = (const f32x4*)(x + (size_t)m * (N * N));
    f32x4* ov = (f32x4*)(out + (size_t)m * (N * N));
#pragma unroll
    for (int k = 0; k < 16; ++k) {
        f32x4 v = xv[k];
        M[4 * k + 0] = __expf(v.x);
        M[4 * k + 1] = __expf(v.y);
        M[4 * k + 2] = __expf(v.z);
        M[4 * k + 3] = __expf(v.w);
    }
    for (int it = 0; it < num_iters; ++it) {
#pragma unroll
        for (int r = 0; r < N; ++r) {
            float s = 0.f;
#pragma unroll
            for (int c = 0; c < N; ++c) s += M[r * N + c];
            float inv = __builtin_amdgcn_rcpf(s);
#pragma unroll
            for (int c = 0; c < N; ++c) M[r * N + c] *= inv;
        }
#pragma unroll
        for (int c = 0; c < N; ++c) {
            float s = 0.f;
#pragma unroll
            for (int r = 0; r < N; ++r) s += M[r * N + c];
            float inv = __builtin_amdgcn_rcpf(s);
#pragma unroll
            for (int r = 0; r < N; ++r) M[r * N + c] *= inv;
        }
    }
#pragma unroll
    for (int k = 0; k < 16; ++k) {
        f32x4 v = {M[4 * k], M[4 * k + 1], M[4 * k + 2], M[4 * k + 3]};
        ov[k] = v;
    }
}

extern "C" void kernel_launch(void* const* d_in, const int* in_sizes, int n_in,
                              void* d_out, int out_size, void* d_ws, size_t ws_size,
                              hipStream_t stream) {
    const float* x = (const float*)d_in[0];
    const int* num_iters = (const int*)d_in[1];
    float* out = (float*)d_out;

    int B = in_sizes[0] / (N * N);  // number of 8x8 matrices (1048576)
    int nwaves = B / 32;
    int nfull = nwaves * 32;

    if (nwaves > 0) {
        long long threads = (long long)nwaves * 64;
        int block = 256;
        long long grid = (threads + block - 1) / block;
        sinkhorn8_kernel<<<(int)grid, block, 0, stream>>>(x, out, num_iters, nwaves);
    }
    int tail = B - nfull;
    if (tail > 0) {
        sinkhorn8_tail<<<1, 64, 0, stream>>>(x, out, num_iters, nfull, B);
    }
}

// Round 7
// 434.176 us; speedup vs baseline: 1.0677x; 1.0023x over previous
//
#include <hip/hip_runtime.h>

// Sinkhorn-Knopp on B independent 8x8 fp32 matrices.
//
// R7 = R2's dense memory pattern x R6's ILP.
//
// Evidence: R2 (1 float4/lane, dense 1KiB per wave instruction, 4 mats/wave)
// ran ~124us but was latency-bound (one dep chain). R6 (row/lane, 32
// mats/wave) ran ~147us: each lane's 16B sat at 32B stride, so every
// load/store instruction spanned 2KiB at 50% density -> 2x lines/sectors per
// vector-memory instruction + partial-sector stores. Memory pattern beats
// ILP; R7 takes both.
//
// Layout: 16 threads per matrix, lane owns one float4 (half a row), with the
// R2 lane-bit remap inside each 16-lane group (t = lane & 15):
//   row bits = lane bits {0,1,3}:  row = (t&3) | ((t>>1)&4)
//   half-col = lane bit 2:         h = (t>>2)&1
// -> every load/store instruction covers one contiguous 1KiB segment
//    (permuted within 256B quarters), 8 cache lines, full-line stores.
//
// Each thread runs FOUR chains from four consecutive 1KiB segments
// (wave covers float4 [w*256, w*256+256) = 16 matrices). All 4 loads issue
// up-front; 4 independent Sinkhorn chains interleave through the 5 serial
// iterations.
//
// Row normalize: local half-row sum + partner at lane xor 4 (1 ds_swizzle
//   per chain-iter; 20/thread for 16 matrices = 1.25/matrix, negligible).
// Col normalize: butterfly across 8 rows = lane xor {1,2,8}, all DPP:
//   xor1 -> quad_perm [1,0,3,2] (0xB1)
//   xor2 -> quad_perm [2,3,0,1] (0x4E)
//   xor8 -> row_ror:8 (0x128)
//
// Issue cost ~15 cyc/matrix/CU vs ~50 cyc/matrix/CU HBM floor (512 MiB /
// ~6.3 TB/s ~= 85us) -> memory-bound.

#define N 8

typedef float f32x4 __attribute__((ext_vector_type(4)));

template <int CTRL>
__device__ __forceinline__ float dpp_xor(float x) {
    int r = __builtin_amdgcn_update_dpp(0, __float_as_int(x), CTRL, 0xF, 0xF, true);
    return __int_as_float(r);
}

__device__ __forceinline__ void exp4(f32x4& v) {
    v.x = __expf(v.x);
    v.y = __expf(v.y);
    v.z = __expf(v.z);
    v.w = __expf(v.w);
}

__device__ __forceinline__ void row_norm(f32x4& v) {
    float rs = (v.x + v.y) + (v.z + v.w);
    rs += __shfl_xor(rs, 4, 64);  // partner half-row at lane xor 4
    float rinv = __builtin_amdgcn_rcpf(rs);
    v.x *= rinv;
    v.y *= rinv;
    v.z *= rinv;
    v.w *= rinv;
}

__device__ __forceinline__ void col_norm(f32x4& v) {
    float cx = v.x, cy = v.y, cz = v.z, cw = v.w;
    cx += dpp_xor<0xB1>(cx);  cy += dpp_xor<0xB1>(cy);
    cz += dpp_xor<0xB1>(cz);  cw += dpp_xor<0xB1>(cw);
    cx += dpp_xor<0x4E>(cx);  cy += dpp_xor<0x4E>(cy);
    cz += dpp_xor<0x4E>(cz);  cw += dpp_xor<0x4E>(cw);
    cx += dpp_xor<0x128>(cx); cy += dpp_xor<0x128>(cy);
    cz += dpp_xor<0x128>(cz); cw += dpp_xor<0x128>(cw);
    v.x *= __builtin_amdgcn_rcpf(cx);
    v.y *= __builtin_amdgcn_rcpf(cy);
    v.z *= __builtin_amdgcn_rcpf(cz);
    v.w *= __builtin_amdgcn_rcpf(cw);
}

__global__ __launch_bounds__(256) void sinkhorn8_kernel(
    const float* __restrict__ x,
    float* __restrict__ out,
    const int* __restrict__ num_iters_p,
    int nwaves)  // number of 16-matrix waves
{
    int T = blockIdx.x * blockDim.x + threadIdx.x;
    int w = T >> 6;  // wave id: matrices [w*16, w*16+16)
    if (w >= nwaves) return;

    const int num_iters = *num_iters_p;

    int l = T & 63;
    int g = l >> 4;          // 16-lane group -> matrix within segment
    int t = l & 15;
    int h = (t >> 2) & 1;    // half of the row
    int row = (t & 3) | ((t >> 1) & 4);

    // Lane's float4 slot inside each dense 1KiB segment; 64 lanes cover
    // the segment exactly once (g*16 + row*2 + h is a bijection on [0,64)).
    size_t base = (size_t)w * 256 + (size_t)(g * 16 + row * 2 + h);

    const f32x4* x4 = (const f32x4*)x;
    f32x4* o4 = (f32x4*)out;

    // Four chains from four consecutive dense segments, loads up-front.
    f32x4 A = x4[base + 0];
    f32x4 Bv = x4[base + 64];
    f32x4 C = x4[base + 128];
    f32x4 D = x4[base + 192];

    exp4(A); exp4(Bv); exp4(C); exp4(D);

    for (int it = 0; it < num_iters; ++it) {
        row_norm(A); row_norm(Bv); row_norm(C); row_norm(D);
        col_norm(A); col_norm(Bv); col_norm(C); col_norm(D);
    }

    o4[base + 0] = A;
    o4[base + 64] = Bv;
    o4[base + 128] = C;
    o4[base + 192] = D;
}

// Tail (B % 16 != 0): one thread per matrix. Not launched for B = 1048576.
__global__ __launch_bounds__(64) void sinkhorn8_tail(
    const float* __restrict__ x,
    float* __restrict__ out,
    const int* __restrict__ num_iters_p,
    int nfull, int B)
{
    int m = nfull + blockIdx.x * blockDim.x + threadIdx.x;
    if (m >= B) return;
    const int num_iters = *num_iters_p;

    float M[N * N];
    const f32x4* xv = (const f32x4*)(x + (size_t)m * (N * N));
    f32x4* ov = (f32x4*)(out + (size_t)m * (N * N));
#pragma unroll
    for (int k = 0; k < 16; ++k) {
        f32x4 v = xv[k];
        M[4 * k + 0] = __expf(v.x);
        M[4 * k + 1] = __expf(v.y);
        M[4 * k + 2] = __expf(v.z);
        M[4 * k + 3] = __expf(v.w);
    }
    for (int it = 0; it < num_iters; ++it) {
#pragma unroll
        for (int r = 0; r < N; ++r) {
            float s = 0.f;
#pragma unroll
            for (int c = 0; c < N; ++c) s += M[r * N + c];
            float inv = __builtin_amdgcn_rcpf(s);
#pragma unroll
            for (int c = 0; c < N; ++c) M[r * N + c] *= inv;
        }
#pragma unroll
        for (int c = 0; c < N; ++c) {
            float s = 0.f;
#pragma unroll
            for (int r = 0; r < N; ++r) s += M[r * N + c];
            float inv = __builtin_amdgcn_rcpf(s);
#pragma unroll
            for (int r = 0; r < N; ++r) M[r * N + c] *= inv;
        }
    }
#pragma unroll
    for (int k = 0; k < 16; ++k) {
        f32x4 v = {M[4 * k], M[4 * k + 1], M[4 * k + 2], M[4 * k + 3]};
        ov[k] = v;
    }
}

extern "C" void kernel_launch(void* const* d_in, const int* in_sizes, int n_in,
                              void* d_out, int out_size, void* d_ws, size_t ws_size,
                              hipStream_t stream) {
    const float* x = (const float*)d_in[0];
    const int* num_iters = (const int*)d_in[1];
    float* out = (float*)d_out;

    int B = in_sizes[0] / (N * N);  // number of 8x8 matrices (1048576)
    int nwaves = B / 16;
    int nfull = nwaves * 16;

    if (nwaves > 0) {
        long long threads = (long long)nwaves * 64;
        int block = 256;
        long long grid = (threads + block - 1) / block;
        sinkhorn8_kernel<<<(int)grid, block, 0, stream>>>(x, out, num_iters, nwaves);
    }
    int tail = B - nfull;
    if (tail > 0) {
        sinkhorn8_tail<<<1, 64, 0, stream>>>(x, out, num_iters, nfull, B);
    }
}